// Round 12
// baseline (94.242 us; speedup 1.0000x reference)
//
#include <hip/hip_runtime.h>
#include <hip/hip_bf16.h>

typedef __bf16 bf16x8 __attribute__((ext_vector_type(8)));
typedef float  f32x4  __attribute__((ext_vector_type(4)));
typedef float  f32x16 __attribute__((ext_vector_type(16)));

constexpr int Bn = 8192, Dn = 64, On = 256;

// async global->LDS DMA: lds dst = wave-uniform base, HW adds lane*16
#define GLD16(g, l) __builtin_amdgcn_global_load_lds( \
    (const __attribute__((address_space(1))) void*)(g), \
    (__attribute__((address_space(3))) void*)(l), 16, 0, 0)

// read-order A-image position: element (m,d) of a 32-row tile
__device__ __forceinline__ int apos(int m, int d) {
    return (((d >> 4) * 64) + (((d >> 3) & 1) * 32) + m) * 8 + (d & 7);
}

// ---- prep: bTsw[o] = betaT read-order image (as R10/R11).
//      waffT[og] = 32x64 affine tile: rows 0-7 = w_hi(o), 8-15 = w_lo(o),
//      16-31 = 0, where w = -2*beta*(beta^T c).  kt[o] = ||beta^T c||^2. ----
__global__ void k_prep(const float* __restrict__ betas, const float* __restrict__ centers,
                       __bf16* __restrict__ bTsw, __bf16* __restrict__ waffT,
                       float* __restrict__ kt) {
    __shared__ float s[64 * 65];                        // +1 pad transpose buffer
    __shared__ float cp[64];
    const int o = blockIdx.x, tid = threadIdx.x;
    const float* bo = betas + (size_t)o * 4096;         // betas[o][d][e]
    for (int j = tid; j < 1024; j += 256) {
        int d = j >> 4, e4 = (j & 15) * 4;
        float4 v = ((const float4*)bo)[j];
        s[d * 65 + e4 + 0] = v.x; s[d * 65 + e4 + 1] = v.y;
        s[d * 65 + e4 + 2] = v.z; s[d * 65 + e4 + 3] = v.w;
    }
    __syncthreads();
    if (tid < 64) {                                     // cp = beta^T c (fp32)
        float a = 0.f;
        for (int d = 0; d < 64; ++d) a += s[d * 65 + tid] * centers[o * 64 + d];
        cp[tid] = a;
    }
    __syncthreads();
    for (int p = tid; p < 4096; p += 256) {             // main A-image (read-order)
        int chunk = p >> 3, j = p & 7;
        int ek = chunk >> 6, lane = chunk & 63;         // ek = et*4 + k
        int e = (ek >> 2) * 32 + (lane & 31);
        int d = ((ek & 3) * 2 + (lane >> 5)) * 8 + j;
        bTsw[(size_t)o * 4096 + p] = (__bf16)s[d * 65 + e];
    }
    if (tid < 64) {                                     // affine tile rows for this o
        int d = tid;
        float w = 0.f;
        for (int e = 0; e < 64; ++e) w += s[d * 65 + e] * cp[e];
        w *= -2.f;
        __bf16 hi = (__bf16)w;
        __bf16 lo = (__bf16)(w - (float)hi);            // hi+lo: bf16^2 residual
        size_t base = (size_t)(o >> 3) * 2048;
        int m = o & 7;
        waffT[base + apos(m, d)]      = hi;
        waffT[base + apos(8 + m, d)]  = lo;
        int mz = 16 + 2 * m;                            // each o zeros 2 spare rows
        waffT[base + apos(mz, d)]     = (__bf16)0.f;
        waffT[base + apos(mz + 1, d)] = (__bf16)0.f;
    }
    if (tid == 0) {
        float s2 = 0.f;
        for (int e = 0; e < 64; ++e) s2 += cp[e] * cp[e];
        kt[o] = s2;
    }
}

// ---- main: block = 4 waves x 256 b, 8 o. C=0 MFMA chains (no cpv loads ->
//      DS pipe = af only, 8 b128/oi). Affine w.x via one extra MFMA chain per
//      bt, once per block; register-only epilogue (no LDS transpose). ----
__global__ void __launch_bounds__(256, 4)
k_main(const float* __restrict__ x, const __bf16* __restrict__ bTsw,
       const __bf16* __restrict__ waffT, const float* __restrict__ kt,
       float* __restrict__ out) {
    __shared__ __align__(16) __bf16 sA[2 * 4096];       // A double-buffer, 16 KB
    __shared__ float sZero[4];

    const int tid = threadIdx.x, wq = tid >> 6, lane = tid & 63;
    const int l31 = lane & 31, l5 = lane >> 5;
    const int bbase = blockIdx.x * 256;                 // x = b-strip (32)
    const int og = blockIdx.y;                          // y = o-group (32)
    const int o0 = og * 8;

    if (tid < 4) sZero[tid] = 0.f;

    // x fragments (one-time, global), B-operand layout: 32 VGPR
    bf16x8 xf[2][4];
#pragma unroll
    for (int bt = 0; bt < 2; ++bt)
#pragma unroll
        for (int kk = 0; kk < 4; ++kk) {
            const float* xp = x + (size_t)(bbase + wq * 64 + bt * 32 + l31) * 64
                                + (kk * 2 + l5) * 8;
            float4 v0 = *(const float4*)xp, v1 = *(const float4*)(xp + 4);
            bf16x8 f;
            f[0] = (__bf16)v0.x; f[1] = (__bf16)v0.y; f[2] = (__bf16)v0.z; f[3] = (__bf16)v0.w;
            f[4] = (__bf16)v1.x; f[5] = (__bf16)v1.y; f[6] = (__bf16)v1.z; f[7] = (__bf16)v1.w;
            xf[bt][kk] = f;
        }
    // affine tile fragments (one-time, global, L2-hot)
    bf16x8 wf[4];
#pragma unroll
    for (int k = 0; k < 4; ++k)
        wf[k] = *(const bf16x8*)(waffT + (size_t)og * 2048 + (size_t)(k * 64 + lane) * 8);

    auto prefetch = [&](int o, __bf16* buf) {
        const __bf16* g = bTsw + (size_t)o * 4096;
        GLD16(g + (size_t)(wq * 128 + lane) * 8,      buf + (wq * 128) * 8);
        GLD16(g + (size_t)(wq * 128 + 64 + lane) * 8, buf + (wq * 128 + 64) * 8);
    };

    prefetch(o0, sA);
    __builtin_amdgcn_s_waitcnt(0x0f70);                 // vmcnt(0): DMA + xf/wf landed
    __syncthreads();                                    // sZero + sA visible

    // zero C-operand, sourced from LDS so any remat is a cheap ds_read
    f32x4 z4 = *(const f32x4*)sZero;
    f32x16 zc;
#pragma unroll
    for (int r4 = 0; r4 < 4; ++r4) ((f32x4*)&zc)[r4] = z4;

    // affine: aff(o', b) = w.x (hi+lo rows), one chain per bt, once per block
    f32x4 aff4[2];
#pragma unroll
    for (int bt = 0; bt < 2; ++bt) {
        f32x16 wa = __builtin_amdgcn_mfma_f32_32x32x16_bf16(wf[0], xf[bt][0], zc, 0, 0, 0);
        wa = __builtin_amdgcn_mfma_f32_32x32x16_bf16(wf[1], xf[bt][1], wa, 0, 0, 0);
        wa = __builtin_amdgcn_mfma_f32_32x32x16_bf16(wf[2], xf[bt][2], wa, 0, 0, 0);
        wa = __builtin_amdgcn_mfma_f32_32x32x16_bf16(wf[3], xf[bt][3], wa, 0, 0, 0);
#pragma unroll
        for (int r = 0; r < 4; ++r)                     // hi + lo rows
            aff4[bt][r] = wa[r] + wa[4 + r];            // aff(o'=l5*4+r, b=bt*32+l31)
    }

    float qd[8];                                        // ||y||^2 for row tid, per o
#pragma unroll
    for (int oi = 0; oi < 8; ++oi) {
        __bf16* cur = sA + (oi & 1) * 4096;
        if (oi < 7) prefetch(o0 + oi + 1, sA + ((oi & 1) ^ 1) * 4096);

        f32x4 qv[2] = {{0,0,0,0},{0,0,0,0}};
#pragma unroll
        for (int et = 0; et < 2; ++et) {
            bf16x8 af[4];                               // stride-1 ds_read_b128
#pragma unroll
            for (int k = 0; k < 4; ++k)
                af[k] = *(const bf16x8*)(cur + (size_t)((et * 4 + k) * 64 + lane) * 8);
#pragma unroll
            for (int bt = 0; bt < 2; ++bt) {
                f32x16 acc = __builtin_amdgcn_mfma_f32_32x32x16_bf16(af[0], xf[bt][0], zc, 0, 0, 0);
                acc = __builtin_amdgcn_mfma_f32_32x32x16_bf16(af[1], xf[bt][1], acc, 0, 0, 0);
                acc = __builtin_amdgcn_mfma_f32_32x32x16_bf16(af[2], xf[bt][2], acc, 0, 0, 0);
                acc = __builtin_amdgcn_mfma_f32_32x32x16_bf16(af[3], xf[bt][3], acc, 0, 0, 0);
                const f32x4* aq = (const f32x4*)&acc;   // packed v_pk_fma squaring
                qv[bt] += aq[0] * aq[0];
                qv[bt] += aq[1] * aq[1];
                qv[bt] += aq[2] * aq[2];
                qv[bt] += aq[3] * aq[3];
            }
        }
        float q0 = (qv[0][0] + qv[0][1]) + (qv[0][2] + qv[0][3]);
        float q1 = (qv[1][0] + qv[1][1]) + (qv[1][2] + qv[1][3]);
        q0 += __shfl_xor(q0, 32, 64);                   // merge l5 halves (full e-sum)
        q1 += __shfl_xor(q1, 32, 64);
        qd[oi] = l5 ? q1 : q0;                          // lane owns row = tid

        __builtin_amdgcn_sched_barrier(0);
        __builtin_amdgcn_s_waitcnt(0x0f70);             // my prefetch landed long ago
        __syncthreads();                                // all quarters in; cur reads done
    }

    // epilogue (registers only): exchange affine halves across l5, add k, exp
    f32x4 affO = aff4[l5];                              // o' = l5*4+r, b = own row
    f32x4 affX;                                         // o' = (1-l5)*4+r, b = own row
#pragma unroll
    for (int r = 0; r < 4; ++r) affX[r] = __shfl_xor(aff4[l5 ^ 1][r], 32, 64);
    f32x4 aff_lo = l5 ? affX : affO;                    // o' = 0..3
    f32x4 aff_hi = l5 ? affO : affX;                    // o' = 4..7
    f32x4 k_lo = *(const f32x4*)(kt + o0);
    f32x4 k_hi = *(const f32x4*)(kt + o0 + 4);
    f32x4 e0, e1;
#pragma unroll
    for (int j = 0; j < 4; ++j) {
        e0[j] = __expf(-(qd[j]     + aff_lo[j] + k_lo[j]));
        e1[j] = __expf(-(qd[4 + j] + aff_hi[j] + k_hi[j]));
    }
    float* op = out + (size_t)(bbase + tid) * 256 + o0;
    *(f32x4*)op       = e0;                             // 32 B burst per row
    *(f32x4*)(op + 4) = e1;
}

extern "C" void kernel_launch(void* const* d_in, const int* in_sizes, int n_in,
                              void* d_out, int out_size, void* d_ws, size_t ws_size,
                              hipStream_t stream) {
    const float* x       = (const float*)d_in[0];   // [8192,64]
    const float* centers = (const float*)d_in[1];   // [256,1,64]
    const float* betas   = (const float*)d_in[2];   // [256,64,64]
    float* out = (float*)d_out;                     // [8192,256] fp32

    char* ws = (char*)d_ws;
    __bf16* bTsw  = (__bf16*)ws;                    // 2 MB (read-order A-images)
    __bf16* waffT = (__bf16*)(ws + 2 * (1 << 20));  // 128 KB (affine tiles)
    float*  ktab  = (float*)(ws + 2 * (1 << 20) + (128 << 10));   // 1 KB

    k_prep<<<dim3(On),                dim3(256), 0, stream>>>(betas, centers, bTsw, waffT, ktab);
    k_main<<<dim3(Bn / 256, On / 8),  dim3(256), 0, stream>>>(x, bTsw, waffT, ktab, out);
}

// Round 13
// 88.654 us; speedup vs baseline: 1.0630x; 1.0630x over previous
//
#include <hip/hip_runtime.h>
#include <hip/hip_bf16.h>

typedef __bf16 bf16x8 __attribute__((ext_vector_type(8)));
typedef float  f32x4  __attribute__((ext_vector_type(4)));

constexpr int Bn = 8192, Dn = 64, On = 256;
constexpr int IMG = 8448;                               // per-o image: 8 KB A + 256 B cp

// async global->LDS DMA: lds dst must be WAVE-UNIFORM; HW adds lane*16
#define GLD16(g, l) __builtin_amdgcn_global_load_lds( \
    (const __attribute__((address_space(1))) void*)(g), \
    (__attribute__((address_space(3))) void*)(l), 16, 0, 0)

// ---- x fp32 -> bf16, chunk-XOR-swizzled: chunk c of row b -> slot c^(b&7) ----
__global__ void k_xcvt(const float* __restrict__ x, __bf16* __restrict__ xbf) {
    int id = blockIdx.x * 256 + threadIdx.x;            // 65536 chunks
    int b = id >> 3, c = id & 7;
    const float* xp = x + (size_t)b * 64 + c * 8;
    float4 v0 = *(const float4*)xp, v1 = *(const float4*)(xp + 4);
    bf16x8 f;
    f[0] = (__bf16)v0.x; f[1] = (__bf16)v0.y; f[2] = (__bf16)v0.z; f[3] = (__bf16)v0.w;
    f[4] = (__bf16)v1.x; f[5] = (__bf16)v1.y; f[6] = (__bf16)v1.z; f[7] = (__bf16)v1.w;
    *(bf16x8*)(xbf + (size_t)b * 64 + ((c ^ (b & 7)) << 3)) = f;
}

// ---- per-o image: A-frags in exact (et,ks,lane) read order + fp32 -cp tail ----
__global__ void k_prep(const float* __restrict__ betas, const float* __restrict__ centers,
                       char* __restrict__ img) {
    __shared__ float s[64 * 65];                        // betaT via padded transpose
    const int o = blockIdx.x, tid = threadIdx.x;
    const float* bo = betas + (size_t)o * 4096;         // betas[o][d][e]
    for (int j = tid; j < 1024; j += 256) {
        int d = j >> 4, e4 = (j & 15) * 4;
        float4 v = ((const float4*)bo)[j];
        s[d * 65 + e4 + 0] = v.x; s[d * 65 + e4 + 1] = v.y;
        s[d * 65 + e4 + 2] = v.z; s[d * 65 + e4 + 3] = v.w;
    }
    __syncthreads();
    __bf16* A = (__bf16*)(img + (size_t)o * IMG);
    for (int p = tid; p < 4096; p += 256) {             // chunk ck=(et*2+ks)*64+lane
        int ck = p >> 3, j = p & 7;
        int et = ck >> 7, ks = (ck >> 6) & 1, ln = ck & 63;
        int e = et * 16 + (ln & 15);
        int d = ks * 32 + ((ln >> 4) << 3) + j;
        A[p] = (__bf16)s[d * 65 + e];
    }
    if (tid < 64) {                                     // -cp[e], natural order, fp32
        float a = 0.f;
        for (int d = 0; d < 64; ++d) a += s[d * 65 + tid] * centers[o * 64 + d];
        ((float*)(img + (size_t)o * IMG + 8192))[tid] = -a;
    }
}

// ---- main: wave = 1 o x 256 b-strip. beta frags + cp REGISTER-RESIDENT
//      (loaded from LDS image that is then clobbered by the x-strip -> the
//      allocator cannot remat them). Hot loop: 2 ds_read + 8 MFMA per 16-b
//      tile, no barriers, no waitcnt, no global ops. ----
__global__ void __launch_bounds__(256, 4)
k_main(const __bf16* __restrict__ xbf, const char* __restrict__ img,
       float* __restrict__ out) {
    __shared__ __align__(16) char smem[4 * IMG];        // 33792 B -> 4 blocks/CU

    const int tid = threadIdx.x, wq = tid >> 6, lane = tid & 63;
    const int col = lane & 15, grp = lane >> 4;
    const int bbase = blockIdx.x * 256;                 // x = b-strip (32)
    const int og = blockIdx.y;                          // y = o-group (64); +-32 id = same XCD
    const int o = og * 4 + wq;

    // phase 1: per-wave DMA of own o-image into private LDS region
    const char* gim = img + (size_t)o * IMG;
    char* lim = smem + wq * IMG;
#pragma unroll
    for (int i = 0; i < 8; ++i)
        GLD16(gim + i * 1024 + lane * 16, lim + i * 1024);
    if (lane < 16)
        GLD16(gim + 8192 + lane * 16, lim + 8192);
    __builtin_amdgcn_s_waitcnt(0x0f70);                 // vmcnt(0): image landed

    // register-resident operands (source clobbered below -> no remat possible)
    bf16x8 af[4][2];                                    // [et][ks]: 32 VGPR
    f32x4  cpv[4];                                      // -cp in C layout: 16 VGPR
#pragma unroll
    for (int et = 0; et < 4; ++et) {
#pragma unroll
        for (int ks = 0; ks < 2; ++ks)
            af[et][ks] = *(const bf16x8*)(lim + ((et * 2 + ks) * 64 + lane) * 16);
        cpv[et] = *(const f32x4*)((const float*)(lim + 8192) + et * 16 + grp * 4);
    }
    __syncthreads();                                    // all waves read their images

    // phase 2: block-coop DMA of pre-swizzled bf16 x-strip (32 KB, straight copy)
    const char* gx = (const char*)(xbf + (size_t)bbase * 64);
#pragma unroll
    for (int i = 0; i < 8; ++i)
        GLD16(gx + (i * 4 + wq) * 1024 + lane * 16, smem + (i * 4 + wq) * 1024);
    __builtin_amdgcn_s_waitcnt(0x0f70);                 // vmcnt(0): strip landed
    __syncthreads();

    // hot loop: 16 b-tiles, nothing but LDS reads + MFMA + pk-fma
    const __bf16* sX = (const __bf16*)smem;
    const int s0 = ((grp ^ (col & 7)) << 3);            // slot of chunk c=grp   (ks=0)
    const int s1 = (((4 + grp) ^ (col & 7)) << 3);      // slot of chunk c=4+grp (ks=1)
    float qd[4];
#pragma unroll
    for (int t = 0; t < 16; ++t) {
        const __bf16* xr = sX + (t * 16 + col) * 64;
        bf16x8 x0 = *(const bf16x8*)(xr + s0);          // d = grp*8 .. +7
        bf16x8 x1 = *(const bf16x8*)(xr + s1);          // d = 32+grp*8 .. +7
        f32x4 qv = {0.f, 0.f, 0.f, 0.f};
#pragma unroll
        for (int et = 0; et < 4; ++et) {
            f32x4 acc = __builtin_amdgcn_mfma_f32_16x16x32_bf16(af[et][0], x0, cpv[et], 0, 0, 0);
            acc = __builtin_amdgcn_mfma_f32_16x16x32_bf16(af[et][1], x1, acc, 0, 0, 0);
            qv += acc * acc;                            // packed fp32 squaring
        }
        float qs = (qv[0] + qv[1]) + (qv[2] + qv[3]);
        qs += __shfl_xor(qs, 16, 64);                   // full 64-e sum in every lane
        qs += __shfl_xor(qs, 32, 64);
        if ((t & 3) == grp) qd[t >> 2] = qs;            // lane keeps b = t*16+col
    }
    __syncthreads();                                    // strip reads done; reuse LDS

    // epilogue: gather [256 b x 4 o] in LDS, one coalesced 16 B store per thread
    float* sQ = (float*)smem;
#pragma unroll
    for (int i = 0; i < 4; ++i)
        sQ[((grp + 4 * i) * 16 + col) * 4 + wq] = qd[i];
    __syncthreads();
    f32x4 q4 = *(const f32x4*)(sQ + tid * 4);
    f32x4 e4;
#pragma unroll
    for (int j = 0; j < 4; ++j) e4[j] = __expf(-q4[j]);
    *(f32x4*)(out + (size_t)(bbase + tid) * 256 + og * 4) = e4;
}

extern "C" void kernel_launch(void* const* d_in, const int* in_sizes, int n_in,
                              void* d_out, int out_size, void* d_ws, size_t ws_size,
                              hipStream_t stream) {
    const float* x       = (const float*)d_in[0];   // [8192,64]
    const float* centers = (const float*)d_in[1];   // [256,1,64]
    const float* betas   = (const float*)d_in[2];   // [256,64,64]
    float* out = (float*)d_out;                     // [8192,256] fp32

    char* ws = (char*)d_ws;
    __bf16* xbf = (__bf16*)ws;                      // 1 MB swizzled bf16 x
    char*   img = ws + (1 << 20);                   // 256 x 8448 B o-images

    k_xcvt<<<dim3(Bn * 64 / 8 / 256), dim3(256), 0, stream>>>(x, xbf);
    k_prep<<<dim3(On),                dim3(256), 0, stream>>>(betas, centers, img);
    k_main<<<dim3(Bn / 256, On / 4),  dim3(256), 0, stream>>>(xbf, img, out);
}